// Round 2
// baseline (960.139 us; speedup 1.0000x reference)
//
#include <hip/hip_runtime.h>
#include <hip/hip_bf16.h>
#include <math.h>

// ---------------------------------------------------------------------------
#define Bq 256
#define DIM_IN 1024
#define DIM_GLOBAL 1024
#define UNITS 512
#define DD 16
#define ATT_ELEMS (256*512*16)       // 2,097,152
#define W_ELEMS   (256*256*512)      // 33,554,432
#define OUT_ELEMS (256*512*16)
#define L2E 1.4426950408889634f

typedef __attribute__((ext_vector_type(8))) short bf16x8;
typedef __attribute__((ext_vector_type(4))) float f32x4;

__device__ __forceinline__ short f2bf(float f) {
    union { float f; unsigned u; } v; v.f = f;
    unsigned u = v.u;
    u += 0x7fffu + ((u >> 16) & 1u);   // round-to-nearest-even
    return (short)(u >> 16);
}

// ---------------------------------------------------------------------------
// C[M,N] = A[M,K] @ B[K,N] + bias[N].  fp32 in/out, bf16 MFMA compute.
// 64x64 tile, BK=32, double-buffered LDS with register prefetch (1 sync/iter).
#define BK 32
#define ASTR 40
#define BSTR 40

__global__ __launch_bounds__(256) void gemm_bias(
    const float* __restrict__ A, const float* __restrict__ B,
    const float* __restrict__ bias, float* __restrict__ C,
    int M, int N, int K)
{
    __shared__ __align__(16) short As[2][64 * ASTR];
    __shared__ __align__(16) short Bs[2][64 * BSTR];

    const int t = threadIdx.x;
    const int lane = t & 63;
    const int wave = t >> 6;
    const int m0 = blockIdx.y * 64;
    const int n0 = blockIdx.x * 64;

    const int wm = (wave >> 1) * 32;
    const int wn = (wave & 1) * 32;
    const int fl = lane & 15;
    const int ko = lane >> 4;

    f32x4 acc00 = {}, acc01 = {}, acc10 = {}, acc11 = {};

    const int ar = t >> 2;             // A row in tile
    const int aq = (t & 3) * 8;        // A k offset
    const int bn = t & 63;             // B col in tile
    const int bk = (t >> 6) * 8;       // B k offset

    const float* aptr = A + (m0 + ar) * K + aq;
    const float* bptr = B + bk * N + n0 + bn;

    float4 av0, av1;
    float bv[8];

    auto issue_loads = [&](int k0) {
        const float* asrc = aptr + k0;
        av0 = *(const float4*)(asrc);
        av1 = *(const float4*)(asrc + 4);
        const float* bsrc = bptr + k0 * N;
        #pragma unroll
        for (int j = 0; j < 8; j++) bv[j] = bsrc[j * N];
    };
    auto write_lds = [&](int buf) {
        bf16x8 p;
        p[0]=f2bf(av0.x); p[1]=f2bf(av0.y); p[2]=f2bf(av0.z); p[3]=f2bf(av0.w);
        p[4]=f2bf(av1.x); p[5]=f2bf(av1.y); p[6]=f2bf(av1.z); p[7]=f2bf(av1.w);
        *(bf16x8*)(&As[buf][ar * ASTR + aq]) = p;
        bf16x8 q;
        #pragma unroll
        for (int j = 0; j < 8; j++) q[j] = f2bf(bv[j]);
        *(bf16x8*)(&Bs[buf][bn * BSTR + bk]) = q;
    };

    issue_loads(0);
    write_lds(0);
    __syncthreads();

    int cur = 0;
    for (int k0 = 0; ; ) {
        const int knext = k0 + BK;
        if (knext < K) issue_loads(knext);   // prefetch into regs

        bf16x8 a0 = *(const bf16x8*)(&As[cur][(wm + 0  + fl) * ASTR + ko * 8]);
        bf16x8 a1 = *(const bf16x8*)(&As[cur][(wm + 16 + fl) * ASTR + ko * 8]);
        bf16x8 b0 = *(const bf16x8*)(&Bs[cur][(wn + 0  + fl) * BSTR + ko * 8]);
        bf16x8 b1 = *(const bf16x8*)(&Bs[cur][(wn + 16 + fl) * BSTR + ko * 8]);
        acc00 = __builtin_amdgcn_mfma_f32_16x16x32_bf16(a0, b0, acc00, 0, 0, 0);
        acc01 = __builtin_amdgcn_mfma_f32_16x16x32_bf16(a0, b1, acc01, 0, 0, 0);
        acc10 = __builtin_amdgcn_mfma_f32_16x16x32_bf16(a1, b0, acc10, 0, 0, 0);
        acc11 = __builtin_amdgcn_mfma_f32_16x16x32_bf16(a1, b1, acc11, 0, 0, 0);

        if (knext >= K) break;
        write_lds(cur ^ 1);
        __syncthreads();
        cur ^= 1;
        k0 = knext;
    }

    #pragma unroll
    for (int r = 0; r < 4; r++) {
        int mrow = m0 + wm + ko * 4 + r;
        int ncol = n0 + wn + fl;
        C[(mrow     ) * N + (ncol     )] = acc00[r] + bias[ncol];
        C[(mrow     ) * N + (ncol + 16)] = acc01[r] + bias[ncol + 16];
        C[(mrow + 16) * N + (ncol     )] = acc10[r] + bias[ncol];
        C[(mrow + 16) * N + (ncol + 16)] = acc11[r] + bias[ncol + 16];
    }
}

// ---------------------------------------------------------------------------
// Decode shared by attn kernels.
// grid = 2048: [ut:16][bt:32][mc:4].  block 256 threads.
// wave = 8 u (lane-fast) x 8 b; the 8 b-lanes load identical K/V rows ->
// coalescer dedups (4x less L2 traffic); stores are u-contiguous.
#define ATTN_GRID 2048

__device__ __forceinline__ void attn_decode(int t, int bid,
                                            int& b, int& u, int& mbase) {
    const int mc = bid & 3;
    const int bt = (bid >> 2) & 31;
    const int ut = bid >> 7;
    const int ul = (t & 7) | ((t >> 6) << 3);   // [0,32), 8 per wave
    u = ut * 32 + ul;
    b = bt * 8 + ((t >> 3) & 7);
    mbase = mc * 64;
}

__global__ __launch_bounds__(256) void attn_stats(
    const float* __restrict__ attention,   // [256,512,16]
    const float* __restrict__ mem_att,     // [256,512,16]
    const float* __restrict__ temperature, // [512]
    float* __restrict__ sums)              // [256,512,8]  (pre-zeroed)
{
    int b, u, mbase;
    attn_decode(threadIdx.x, blockIdx.x, b, u, mbase);

    float q[16];
    {
        const float* ap = attention + (b * UNITS + u) * DD;
        #pragma unroll
        for (int d4 = 0; d4 < 4; d4++) {
            float4 v = *(const float4*)(ap + d4 * 4);
            q[d4*4+0]=v.x; q[d4*4+1]=v.y; q[d4*4+2]=v.z; q[d4*4+3]=v.w;
        }
    }
    const float tmp = temperature[u];

    float gsum[8];
    #pragma unroll
    for (int g = 0; g < 8; g++) gsum[g] = 0.f;

    const float* kbase = mem_att + (mbase * UNITS + u) * DD;

    for (int i = 0; i < 8; i++) {          // 8 x 8 m = 64 m per chunk
        #pragma unroll
        for (int g = 0; g < 8; g++) {
            const int m = mbase + i * 8 + g;
            const float* kp = kbase + (i * 8 + g) * (UNITS * DD);
            float s = 0.f;
            #pragma unroll
            for (int d4 = 0; d4 < 4; d4++) {
                float4 v = *(const float4*)(kp + d4 * 4);
                s += q[d4*4+0]*v.x + q[d4*4+1]*v.y
                   + q[d4*4+2]*v.z + q[d4*4+3]*v.w;
            }
            const float e = exp2f(s * tmp * L2E);
            gsum[g] += (m == b) ? 0.f : e;
        }
    }

    float* sp = sums + (b * UNITS + u) * 8;
    #pragma unroll
    for (int g = 0; g < 8; g++) atomicAdd(sp + g, gsum[g]);
}

__global__ __launch_bounds__(256) void attn_write(
    const float* __restrict__ attention,
    const float* __restrict__ mem_att,
    const float* __restrict__ mem_val,
    const float* __restrict__ temperature,
    const float* __restrict__ sums,        // [256,512,8]
    float* __restrict__ weights_out,       // [256,256,512]
    float* __restrict__ outputs_out)       // [256,512,16] (pre-zeroed)
{
    int b, u, mbase;
    attn_decode(threadIdx.x, blockIdx.x, b, u, mbase);

    float q[16];
    {
        const float* ap = attention + (b * UNITS + u) * DD;
        #pragma unroll
        for (int d4 = 0; d4 < 4; d4++) {
            float4 v = *(const float4*)(ap + d4 * 4);
            q[d4*4+0]=v.x; q[d4*4+1]=v.y; q[d4*4+2]=v.z; q[d4*4+3]=v.w;
        }
    }
    const float tmp = temperature[u];

    float rinv[8];
    {
        const float* sp = sums + (b * UNITS + u) * 8;
        #pragma unroll
        for (int g = 0; g < 8; g++) rinv[g] = 1.0f / (8.0f * sp[g]);
    }

    float acc[16];
    #pragma unroll
    for (int d = 0; d < 16; d++) acc[d] = 0.f;

    const float* kbase = mem_att + (mbase * UNITS + u) * DD;
    const float* vbase = mem_val + (mbase * UNITS + u) * DD;
    float* wrow = weights_out + (b * 256 + mbase) * UNITS + u;

    for (int i = 0; i < 8; i++) {
        #pragma unroll
        for (int g = 0; g < 8; g++) {
            const int mi = i * 8 + g;
            const int m = mbase + mi;
            const float* kp = kbase + mi * (UNITS * DD);
            float s = 0.f;
            #pragma unroll
            for (int d4 = 0; d4 < 4; d4++) {
                float4 v = *(const float4*)(kp + d4 * 4);
                s += q[d4*4+0]*v.x + q[d4*4+1]*v.y
                   + q[d4*4+2]*v.z + q[d4*4+3]*v.w;
            }
            const float w = (m == b) ? 0.f
                           : exp2f(s * tmp * L2E) * rinv[g];
            wrow[mi * UNITS] = w;
            const float* vp = vbase + mi * (UNITS * DD);
            #pragma unroll
            for (int d4 = 0; d4 < 4; d4++) {
                float4 v = *(const float4*)(vp + d4 * 4);
                acc[d4*4+0] += w * v.x; acc[d4*4+1] += w * v.y;
                acc[d4*4+2] += w * v.z; acc[d4*4+3] += w * v.w;
            }
        }
    }

    float* op = outputs_out + (b * UNITS + u) * DD;
    #pragma unroll
    for (int d = 0; d < 16; d++) atomicAdd(op + d, acc[d]);
}

// ---------------------------------------------------------------------------
extern "C" void kernel_launch(void* const* d_in, const int* in_sizes, int n_in,
                              void* d_out, int out_size, void* d_ws, size_t ws_size,
                              hipStream_t stream) {
    const float* x        = (const float*)d_in[0];
    const float* W1       = (const float*)d_in[1];
    const float* b1       = (const float*)d_in[2];
    const float* W2       = (const float*)d_in[3];
    const float* b2       = (const float*)d_in[4];
    const float* temp     = (const float*)d_in[5];
    const float* mem_att  = (const float*)d_in[6];
    const float* mem_val  = (const float*)d_in[7];

    float* out       = (float*)d_out;
    float* attention = out;
    float* weights   = out + ATT_ELEMS;
    float* outputs   = out + ATT_ELEMS + W_ELEMS;

    float* sums = (float*)d_ws;                   // 256*512*8 f32 = 4 MB
    float* h    = weights;                        // gemm scratch, overwritten later

    hipMemsetAsync(sums, 0, (size_t)256 * 512 * 8 * sizeof(float), stream);
    hipMemsetAsync(outputs, 0, (size_t)OUT_ELEMS * sizeof(float), stream);

    dim3 blk(256);
    gemm_bias<<<dim3(DIM_GLOBAL / 64, Bq / 64), blk, 0, stream>>>(
        x, W1, b1, h, Bq, DIM_GLOBAL, DIM_IN);
    gemm_bias<<<dim3((UNITS * DD) / 64, Bq / 64), blk, 0, stream>>>(
        h, W2, b2, attention, Bq, UNITS * DD, DIM_GLOBAL);

    attn_stats<<<dim3(ATTN_GRID), blk, 0, stream>>>(
        attention, mem_att, temp, sums);
    attn_write<<<dim3(ATTN_GRID), blk, 0, stream>>>(
        attention, mem_att, mem_val, temp, sums, weights, outputs);
}

// Round 3
// 581.213 us; speedup vs baseline: 1.6520x; 1.6520x over previous
//
#include <hip/hip_runtime.h>
#include <hip/hip_bf16.h>
#include <math.h>

// ---------------------------------------------------------------------------
#define Bq 256
#define DIM_IN 1024
#define DIM_GLOBAL 1024
#define UNITS 512
#define DD 16
#define ATT_ELEMS (256*512*16)       // 2,097,152
#define W_ELEMS   (256*256*512)      // 33,554,432
#define L2E 1.4426950408889634f

typedef __attribute__((ext_vector_type(8))) short bf16x8;
typedef __attribute__((ext_vector_type(4))) float f32x4;

#define GLOBAL_AS(p) ((const __attribute__((address_space(1))) void*)(p))
#define LDS_AS(p)    ((__attribute__((address_space(3))) void*)(p))

__device__ __forceinline__ ushort f2bf(float f) {
    union { float f; unsigned u; } v; v.f = f;
    unsigned u = v.u;
    u += 0x7fffu + ((u >> 16) & 1u);   // round-to-nearest-even
    return (ushort)(u >> 16);
}

// ---------------------------------------------------------------------------
// f32 -> bf16 flat convert (16B stores), n8 = elems/8
__global__ __launch_bounds__(256) void convert_bf16(
    const float* __restrict__ src, ushort* __restrict__ dst, int n8)
{
    int i = blockIdx.x * 256 + threadIdx.x;
    if (i >= n8) return;
    const float4 v0 = *(const float4*)(src + (size_t)i * 8);
    const float4 v1 = *(const float4*)(src + (size_t)i * 8 + 4);
    bf16x8 p;
    p[0]=f2bf(v0.x); p[1]=f2bf(v0.y); p[2]=f2bf(v0.z); p[3]=f2bf(v0.w);
    p[4]=f2bf(v1.x); p[5]=f2bf(v1.y); p[6]=f2bf(v1.z); p[7]=f2bf(v1.w);
    *(bf16x8*)(dst + (size_t)i * 8) = p;
}

// ---------------------------------------------------------------------------
// W [K x N] f32 row-major -> Wt [N x K] bf16 row-major.  Tile 64k x 32n.
__global__ __launch_bounds__(256) void transpose_to_bf16(
    const float* __restrict__ W, ushort* __restrict__ Wt, int K, int N)
{
    __shared__ float T[64][33];
    const int t = threadIdx.x;
    const int n0 = blockIdx.x * 32;
    const int k0 = blockIdx.y * 64;
    const int nn = t & 31;
    const int kk0 = t >> 5;            // 0..7
    #pragma unroll
    for (int i = 0; i < 8; i++) {
        int kk = kk0 + i * 8;
        T[kk][nn] = W[(size_t)(k0 + kk) * N + n0 + nn];
    }
    __syncthreads();
    const int nr = t >> 4;             // 0..15
    const int kq = (t & 15) * 4;
    #pragma unroll
    for (int i = 0; i < 2; i++) {
        int n = nr + i * 16;
        ushort4 v;
        v.x = f2bf(T[kq + 0][n]);
        v.y = f2bf(T[kq + 1][n]);
        v.z = f2bf(T[kq + 2][n]);
        v.w = f2bf(T[kq + 3][n]);
        *(ushort4*)(&Wt[(size_t)(n0 + n) * K + k0 + kq]) = v;
    }
}

// ---------------------------------------------------------------------------
// C[M,N] = A[M,K] @ Bt[N,K]^T + bias.  bf16 inputs, MFMA, async LDS staging.
// 64x64 tile, BK=64, double-buffered, 1 barrier per K-step.
// LDS chunk mapping: chunk c (16B) -> row=((c>>6)<<3)|(c&7), kchunk=(c>>3)&7.
// Forced layout (global_load_lds: base+lane*16) then gives frag reads at
// shorts offset (row>>3)*512 + j*64 + (row&7)*8 -> banks (row&7)*4: 2-way only.
template<bool BF16OUT>
__global__ __launch_bounds__(256) void gemm_bf16(
    const ushort* __restrict__ A,    // [M,K]
    const ushort* __restrict__ Bt,   // [N,K]
    const float* __restrict__ bias,  // [N]
    void* __restrict__ Cv,
    int M, int N, int K)
{
    __shared__ __align__(16) ushort As[2][64 * 64];
    __shared__ __align__(16) ushort Bs[2][64 * 64];

    const int t = threadIdx.x;
    const int lane = t & 63;
    const int wave = t >> 6;
    const int m0 = blockIdx.y * 64;
    const int n0 = blockIdx.x * 64;
    const int wm = (wave >> 1) * 32;
    const int wn = (wave & 1) * 32;
    const int fl = lane & 15;
    const int ko = lane >> 4;

    const ushort* Ag = A + (size_t)m0 * K;
    const ushort* Bg = Bt + (size_t)n0 * K;

    f32x4 acc00 = {}, acc01 = {}, acc10 = {}, acc11 = {};

    auto stage = [&](int buf, int k0) {
        #pragma unroll
        for (int cc = 0; cc < 2; cc++) {
            const int c = t + cc * 256;
            const int row = ((c >> 6) << 3) | (c & 7);
            const int kc = (c >> 3) & 7;
            __builtin_amdgcn_global_load_lds(
                GLOBAL_AS(Ag + (size_t)row * K + k0 + kc * 8),
                LDS_AS(&As[buf][c * 8]), 16, 0, 0);
            __builtin_amdgcn_global_load_lds(
                GLOBAL_AS(Bg + (size_t)row * K + k0 + kc * 8),
                LDS_AS(&Bs[buf][c * 8]), 16, 0, 0);
        }
    };
    auto frag = [&](const ushort* base, int row, int j) -> bf16x8 {
        return *(const bf16x8*)(base + ((row >> 3) << 9) + (j << 6) + ((row & 7) << 3));
    };

    stage(0, 0);
    int cur = 0;
    for (int k0 = 0; k0 < K; k0 += 64) {
        __syncthreads();                       // drains vmcnt -> buf `cur` ready
        if (k0 + 64 < K) stage(cur ^ 1, k0 + 64);  // async into other buf
        #pragma unroll
        for (int s = 0; s < 2; s++) {
            const int j = s * 4 + ko;
            bf16x8 a0 = frag(As[cur], wm + fl,      j);
            bf16x8 a1 = frag(As[cur], wm + 16 + fl, j);
            bf16x8 b0 = frag(Bs[cur], wn + fl,      j);
            bf16x8 b1 = frag(Bs[cur], wn + 16 + fl, j);
            acc00 = __builtin_amdgcn_mfma_f32_16x16x32_bf16(a0, b0, acc00, 0, 0, 0);
            acc01 = __builtin_amdgcn_mfma_f32_16x16x32_bf16(a0, b1, acc01, 0, 0, 0);
            acc10 = __builtin_amdgcn_mfma_f32_16x16x32_bf16(a1, b0, acc10, 0, 0, 0);
            acc11 = __builtin_amdgcn_mfma_f32_16x16x32_bf16(a1, b1, acc11, 0, 0, 0);
        }
        cur ^= 1;
    }

    #pragma unroll
    for (int r = 0; r < 4; r++) {
        const int mrow = m0 + wm + ko * 4 + r;
        const int nc = n0 + wn + fl;
        const float v00 = acc00[r] + bias[nc];
        const float v01 = acc01[r] + bias[nc + 16];
        const float v10 = acc10[r] + bias[nc];
        const float v11 = acc11[r] + bias[nc + 16];
        if constexpr (BF16OUT) {
            ushort* C = (ushort*)Cv;
            C[(size_t)(mrow     ) * N + nc     ] = f2bf(v00);
            C[(size_t)(mrow     ) * N + nc + 16] = f2bf(v01);
            C[(size_t)(mrow + 16) * N + nc     ] = f2bf(v10);
            C[(size_t)(mrow + 16) * N + nc + 16] = f2bf(v11);
        } else {
            float* C = (float*)Cv;
            C[(size_t)(mrow     ) * N + nc     ] = v00;
            C[(size_t)(mrow     ) * N + nc + 16] = v01;
            C[(size_t)(mrow + 16) * N + nc     ] = v10;
            C[(size_t)(mrow + 16) * N + nc + 16] = v11;
        }
    }
}

// ---------------------------------------------------------------------------
// Fused scores -> grouped softmax (no-max, valid range) -> weights + PV.
// Round-1 layout (coalesced 128B weight stores); __syncthreads every 8 m keeps
// the 4 waves on the same 32KB K/V window so L1 serves cross-wave re-reads.
__global__ __launch_bounds__(256) void attn_fused(
    const float* __restrict__ attention,   // [256,512,16]
    const float* __restrict__ mem_att,     // [256,512,16]
    const float* __restrict__ mem_val,     // [256,512,16]
    const float* __restrict__ temperature, // [512]
    float* __restrict__ weights_out,       // [256,256,512]
    float* __restrict__ outputs_out)       // [256,512,16]
{
    const int t = threadIdx.x;
    const int ublk = blockIdx.x & 15;
    const int bblk = blockIdx.x >> 4;
    const int u = ublk * 32 + (t & 31);
    const int b = bblk * 8 + (t >> 5);

    float q[16];
    {
        const float* ap = attention + (size_t)(b * UNITS + u) * DD;
        #pragma unroll
        for (int d4 = 0; d4 < 4; d4++) {
            float4 v = *(const float4*)(ap + d4 * 4);
            q[d4*4+0]=v.x; q[d4*4+1]=v.y; q[d4*4+2]=v.z; q[d4*4+3]=v.w;
        }
    }
    const float tmp = temperature[u] * L2E;

    float gsum[8];
    #pragma unroll
    for (int g = 0; g < 8; g++) gsum[g] = 0.f;

    const float* kbase = mem_att + (size_t)u * DD;

    // ---- pass 1: sum(exp) per group ----
    for (int m8 = 0; m8 < 256; m8 += 8) {
        __syncthreads();
        #pragma unroll
        for (int g = 0; g < 8; g++) {
            const int m = m8 + g;
            const float* kp = kbase + (size_t)m * (UNITS * DD);
            float s = 0.f;
            #pragma unroll
            for (int d4 = 0; d4 < 4; d4++) {
                float4 v = *(const float4*)(kp + d4 * 4);
                s += q[d4*4+0]*v.x + q[d4*4+1]*v.y
                   + q[d4*4+2]*v.z + q[d4*4+3]*v.w;
            }
            const float e = exp2f(s * tmp);
            gsum[g] += (m == b) ? 0.f : e;
        }
    }

    float rinv[8];
    #pragma unroll
    for (int g = 0; g < 8; g++) rinv[g] = 1.0f / (8.0f * gsum[g]);

    float acc[16];
    #pragma unroll
    for (int d = 0; d < 16; d++) acc[d] = 0.f;

    const float* vbase = mem_val + (size_t)u * DD;
    float* wrow = weights_out + (size_t)b * (256 * UNITS) + u;

    // ---- pass 2: recompute, write weights (coalesced), accumulate PV ----
    for (int m8 = 0; m8 < 256; m8 += 8) {
        __syncthreads();
        #pragma unroll
        for (int g = 0; g < 8; g++) {
            const int m = m8 + g;
            const float* kp = kbase + (size_t)m * (UNITS * DD);
            float s = 0.f;
            #pragma unroll
            for (int d4 = 0; d4 < 4; d4++) {
                float4 v = *(const float4*)(kp + d4 * 4);
                s += q[d4*4+0]*v.x + q[d4*4+1]*v.y
                   + q[d4*4+2]*v.z + q[d4*4+3]*v.w;
            }
            const float w = (m == b) ? 0.f : exp2f(s * tmp) * rinv[g];
            wrow[(size_t)m * UNITS] = w;       // 128B contiguous per 32 lanes
            const float* vp = vbase + (size_t)m * (UNITS * DD);
            #pragma unroll
            for (int d4 = 0; d4 < 4; d4++) {
                float4 v = *(const float4*)(vp + d4 * 4);
                acc[d4*4+0] += w * v.x; acc[d4*4+1] += w * v.y;
                acc[d4*4+2] += w * v.z; acc[d4*4+3] += w * v.w;
            }
        }
    }

    float* op = outputs_out + (size_t)(b * UNITS + u) * DD;
    #pragma unroll
    for (int d4 = 0; d4 < 4; d4++) {
        float4 v;
        v.x = acc[d4*4+0]; v.y = acc[d4*4+1];
        v.z = acc[d4*4+2]; v.w = acc[d4*4+3];
        *(float4*)(op + d4 * 4) = v;
    }
}

// ---------------------------------------------------------------------------
extern "C" void kernel_launch(void* const* d_in, const int* in_sizes, int n_in,
                              void* d_out, int out_size, void* d_ws, size_t ws_size,
                              hipStream_t stream) {
    const float* x        = (const float*)d_in[0];  // [256,1024]
    const float* W1       = (const float*)d_in[1];  // [1024,1024]
    const float* b1       = (const float*)d_in[2];
    const float* W2       = (const float*)d_in[3];  // [1024,8192]
    const float* b2       = (const float*)d_in[4];
    const float* temp     = (const float*)d_in[5];
    const float* mem_att  = (const float*)d_in[6];
    const float* mem_val  = (const float*)d_in[7];

    float* out       = (float*)d_out;
    float* attention = out;
    float* weights   = out + ATT_ELEMS;
    float* outputs   = out + ATT_ELEMS + W_ELEMS;

    // workspace layout (bf16 as ushort)
    ushort* xb  = (ushort*)d_ws;                         // 256x1024
    ushort* W1t = xb  + 256 * 1024;                      // 1024x1024 (N x K)
    ushort* W2t = W1t + 1024 * 1024;                     // 8192x1024 (N x K)
    ushort* hb  = W2t + (size_t)8192 * 1024;             // 256x1024

    dim3 blk(256);
    convert_bf16<<<dim3((256 * 1024 / 8 + 255) / 256), blk, 0, stream>>>(
        x, xb, 256 * 1024 / 8);
    transpose_to_bf16<<<dim3(1024 / 32, 1024 / 64), blk, 0, stream>>>(
        W1, W1t, 1024, 1024);
    transpose_to_bf16<<<dim3(8192 / 32, 1024 / 64), blk, 0, stream>>>(
        W2, W2t, 1024, 8192);

    // h = x @ W1 + b1  (bf16 out)
    gemm_bf16<true><<<dim3(DIM_GLOBAL / 64, Bq / 64), blk, 0, stream>>>(
        xb, W1t, b1, hb, Bq, DIM_GLOBAL, DIM_IN);
    // attention = h @ W2 + b2  (f32 out)
    gemm_bf16<false><<<dim3((UNITS * DD) / 64, Bq / 64), blk, 0, stream>>>(
        hb, W2t, b2, attention, Bq, UNITS * DD, DIM_GLOBAL);

    attn_fused<<<dim3(512), blk, 0, stream>>>(
        attention, mem_att, mem_val, temp, weights, outputs);
}